// Round 7
// baseline (201.357 us; speedup 1.0000x reference)
//
#include <hip/hip_runtime.h>
#include <stdint.h>

// Problem constants (fixed by reference setup_inputs)
#define BB 8
#define SS 2048
#define DD 2048
#define EE 8
#define CHUNKS 128          // chunks per batch
#define ROWS 16             // rows per chunk (SS / CHUNKS)
#define NBLK (BB * CHUNKS)  // 1024 blocks = 4 blocks/CU, 16 waves/CU
#define AUX  (NBLK * 9)     // float offset of W-stat aux region in pbuf

typedef float f4 __attribute__((ext_vector_type(4)));

// Kernel 1: stream x (fp32). Per block = one (b, chunk of 16 rows).
// COALESCING: thread t owns cols [t*4, t*4+4) and [1024+t*4, 1024+t*4+4)
// -> every global_load_dwordx4 is lane-contiguous (64 lanes x 16 B = 1 KiB).
// Partials are written TRANSPOSED (pout[j*NBLK + bid]) so k_finish's reduce
// reads contiguous arrays (R6's record-major layout was 288B-stride,
// 64 line-requests per load instruction).
// W-stat (sum/sumsq) computed ONLY by block 0 (was dead VALU in 2047 blocks).
__global__ __launch_bounds__(256) void k_partial(const float* __restrict__ x,
                                                 const float* __restrict__ W,
                                                 float* __restrict__ pout) {
    const int t = threadIdx.x;
    const int bid = blockIdx.x;
    const int b = bid >> 7;              // / CHUNKS
    const int chunk = bid & (CHUNKS - 1);
    const int c0 = t * 4;                // first owned f4 column
    const int c1 = 1024 + t * 4;         // second owned f4 column

    const float* xp = x + ((size_t)b * SS + (size_t)chunk * ROWS) * DD;

    // ---- column sums over 16 rows, 4 groups of 4 rows (8 loads in flight)
    f4 s0 = {0.f, 0.f, 0.f, 0.f}, s1 = {0.f, 0.f, 0.f, 0.f};
#pragma unroll
    for (int gq = 0; gq < 4; ++gq) {
        const float* p = xp + (size_t)gq * 4 * DD;
        f4 a0 = *(const f4*)(p + c0);
        f4 b0 = *(const f4*)(p + c1);
        f4 a1 = *(const f4*)(p + DD + c0);
        f4 b1 = *(const f4*)(p + DD + c1);
        f4 a2 = *(const f4*)(p + 2 * DD + c0);
        f4 b2 = *(const f4*)(p + 2 * DD + c1);
        f4 a3 = *(const f4*)(p + 3 * DD + c0);
        f4 b3 = *(const f4*)(p + 3 * DD + c1);
        s0 += a0; s1 += b0;
        s0 += a1; s1 += b1;
        s0 += a2; s1 += b2;
        s0 += a3; s1 += b3;
    }

    // ---- epilogue: 9 partials = 8 expert dots (W is L2-hot) + total x sum
    float vals[9];
    vals[8] = s0[0] + s0[1] + s0[2] + s0[3] + s1[0] + s1[1] + s1[2] + s1[3];
#pragma unroll
    for (int e = 0; e < 8; ++e) {
        f4 wa = *(const f4*)(W + e * DD + c0);
        f4 wb = *(const f4*)(W + e * DD + c1);
        float acc = 0.f;
#pragma unroll
        for (int j = 0; j < 4; ++j) acc = fmaf(s0[j], wa[j], acc);
#pragma unroll
        for (int j = 0; j < 4; ++j) acc = fmaf(s1[j], wb[j], acc);
        vals[e] = acc;
    }

    // ---- wave butterfly reduce of the 9 partials, then cross-wave via LDS
#pragma unroll
    for (int off = 32; off >= 1; off >>= 1) {
#pragma unroll
        for (int j = 0; j < 9; ++j) vals[j] += __shfl_xor(vals[j], off, 64);
    }

    __shared__ float lw[4][9];
    const int lane = t & 63, wid = t >> 6;
    if (lane == 0) {
#pragma unroll
        for (int j = 0; j < 9; ++j) lw[wid][j] = vals[j];
    }
    __syncthreads();
    if (t < 9) {
        // transposed: slot t is a contiguous [NBLK] array
        pout[t * NBLK + bid] = lw[0][t] + lw[1][t] + lw[2][t] + lw[3][t];
    }

    // ---- block 0 only: W row stats (reloads W fragments — L1-hot here)
    if (bid == 0) {
        float wsv[8], wqv[8];
#pragma unroll
        for (int e = 0; e < 8; ++e) {
            f4 wa = *(const f4*)(W + e * DD + c0);
            f4 wb = *(const f4*)(W + e * DD + c1);
            float ws = wa[0] + wa[1] + wa[2] + wa[3] + wb[0] + wb[1] + wb[2] + wb[3];
            float wq = 0.f;
#pragma unroll
            for (int j = 0; j < 4; ++j) wq = fmaf(wa[j], wa[j], wq);
#pragma unroll
            for (int j = 0; j < 4; ++j) wq = fmaf(wb[j], wb[j], wq);
            wsv[e] = ws;
            wqv[e] = wq;
        }
#pragma unroll
        for (int off = 32; off >= 1; off >>= 1) {
#pragma unroll
            for (int e = 0; e < 8; ++e) {
                wsv[e] += __shfl_xor(wsv[e], off, 64);
                wqv[e] += __shfl_xor(wqv[e], off, 64);
            }
        }
        __shared__ float lw2[4][16];
        if (lane == 0) {
#pragma unroll
            for (int e = 0; e < 8; ++e) {
                lw2[wid][e] = wsv[e];
                lw2[wid][8 + e] = wqv[e];
            }
        }
        __syncthreads();
        if (t < 16) {
            pout[AUX + t] = lw2[0][t] + lw2[1][t] + lw2[2][t] + lw2[3][t];
        }
    }
}

// Kernel 2: single block. W stats arrive pre-reduced in aux (16 floats).
// Phase A (transposed pbuf): group g (32 threads) reduces batch g; for each
//   slot j, thread l loads ONE f4 at pbuf[j*NBLK + g*128 + 4*l] — 32 lanes
//   x 16 B contiguous, 9 loads/thread total (was 18 uncoalesced).
// Phase C: 8 threads: scores -> softmax -> top2 -> outputs.
__global__ __launch_bounds__(256) void k_finish(const float* __restrict__ pin,
                                                const float* __restrict__ gain,
                                                const float* __restrict__ istd,
                                                const float* __restrict__ noise,
                                                float* __restrict__ out) {
    const int t = threadIdx.x;
    const int l = t & 31;
    const int g = t >> 5;   // batch index in phase A

    __shared__ float sdot[BB][9];
    __shared__ float smean[EE], sscale[EE];

    // ---- W stats from aux (already fully reduced by k_partial block 0)
    if (t < EE) {
        const float s = pin[AUX + t];
        const float q = pin[AUX + 8 + t];
        const float mean = s / (float)DD;
        float var = (q - (float)DD * mean * mean) / (float)(DD - 1);
        var = fmaxf(var, 0.f);
        const float stdv = sqrtf(var) + 1e-5f;   // torch-style unbiased std + EPS
        smean[t] = mean;
        sscale[t] = istd[t] / stdv * gain[t];
    }

    // ---- Phase A: coalesced slot-major reduce
    float sums[9];
#pragma unroll
    for (int j = 0; j < 9; ++j) {
        f4 v = *(const f4*)(pin + j * NBLK + g * CHUNKS + 4 * l);
        sums[j] = v[0] + v[1] + v[2] + v[3];
    }
#pragma unroll
    for (int off = 16; off >= 1; off >>= 1) {
#pragma unroll
        for (int j = 0; j < 9; ++j) sums[j] += __shfl_xor(sums[j], off, 64);
    }
    if (l < 9) sdot[g][l] = sums[l];
    __syncthreads();

    // ---- Phase C: one thread per batch row
    if (t < BB) {
        const int b = t;
        const float xtot = sdot[b][8];
        float p[EE];
        float m = -1e30f;
#pragma unroll
        for (int e = 0; e < EE; ++e) {
            float sc = sscale[e] * (sdot[b][e] - smean[e] * xtot) * (1.f / (float)SS)
                     + noise[b * EE + e];
            p[e] = sc;
            m = fmaxf(m, sc);
        }
        float sum = 0.f;
#pragma unroll
        for (int e = 0; e < EE; ++e) { p[e] = __expf(p[e] - m); sum += p[e]; }
        const float inv = 1.f / sum;
#pragma unroll
        for (int e = 0; e < EE; ++e) p[e] *= inv;

        // top-2, ties -> lowest index first (strict >, ascending scan)
        int i1 = 0;
#pragma unroll
        for (int e = 1; e < EE; ++e) if (p[e] > p[i1]) i1 = e;
        int i2 = (i1 == 0) ? 1 : 0;
#pragma unroll
        for (int e = 0; e < EE; ++e) if (e != i1 && p[e] > p[i2]) i2 = e;

        // combine tensor [B,E]
#pragma unroll
        for (int e = 0; e < EE; ++e) {
            float v = (e == i1) ? p[i1] : ((e == i2) ? p[i2] : 0.f);
            out[b * EE + e] = v;
        }
        // indices [B,2] as numeric values
        out[64 + b * 2 + 0] = (float)i1;
        out[64 + b * 2 + 1] = (float)i2;
        // topk gate scores [B,2]
        out[80 + b * 2 + 0] = p[i1];
        out[80 + b * 2 + 1] = p[i2];
    }
}

extern "C" void kernel_launch(void* const* d_in, const int* in_sizes, int n_in,
                              void* d_out, int out_size, void* d_ws, size_t ws_size,
                              hipStream_t stream) {
    const float* x     = (const float*)d_in[0];
    const float* W     = (const float*)d_in[1];
    const float* gain  = (const float*)d_in[2];
    const float* istd  = (const float*)d_in[3];
    const float* noise = (const float*)d_in[4];
    // d_in[5] = top_k (==2) — hardcoded per reference.

    float* pbuf = (float*)d_ws;          // NBLK*9 + 16 floats ~= 37 KB
    float* out  = (float*)d_out;         // 96 fp32

    k_partial<<<dim3(NBLK), dim3(256), 0, stream>>>(x, W, pbuf);
    k_finish<<<dim3(1), dim3(256), 0, stream>>>(pbuf, gain, istd, noise, out);
}